// Round 4
// baseline (338.227 us; speedup 1.0000x reference)
//
#include <hip/hip_runtime.h>
#include <stdint.h>

#define T_LEN 200
#define B_SZ  1024
#define D_DIM 128
#define LOG2E 1.44269504088896340736f

typedef __bf16 bf16_t;
typedef __bf16 bf16x8 __attribute__((ext_vector_type(8)));
typedef float  f32x4  __attribute__((ext_vector_type(4)));

union BF8 { bf16x8 v; bf16_t e[8]; };
struct F8 { float4 a, b; };

__device__ inline float rcp_f(float x) { return __builtin_amdgcn_rcpf(x); }

// Pack two f32 -> bf16x2 dword, RNE (single HW instr).
__device__ inline uint32_t cvt_pk_bf16(float a, float b) {
  uint32_t r;
  asm("v_cvt_pk_bf16_f32 %0, %1, %2" : "=v"(r) : "v"(a), "v"(b));
  return r;
}

// LDS-only barrier: wait LDS ops, leave global loads (vmcnt) in flight.
#define BAR_LDS() asm volatile("s_waitcnt lgkmcnt(0)\n\ts_barrier" ::: "memory")

// ---------------------------------------------------------------------------
// Fused AUGRU scan. Round-4 STRUCTURAL change: 4 waves x 32 cols (was 8 x 16).
// Rationale: per-CU-step LDS read traffic = waves * 8KB (every wave re-reads
// the block-uniform 16x128 A-tiles of s and x). 8 waves = 64KB/step ~ 770cy
// of LDS throughput; 4 waves = 32KB. Also: 1 wave/SIMD (critical wave owns
// all issue slots; round-3 showed 2 lockstep waves/SIMD contend), 2 col-tiles
// give every MFMA/trans chain 2x ILP, barrier participants 8->4.
// __launch_bounds__(256,1): full 512-reg unified VGPR/AGPR budget for the
// ~192-reg doubled B-fragment set. 64 blocks x 256 thr; block bb owns batch
// rows [16*bb, 16*bb+16); wave w owns cols [32w, 32w+32) as 2 MFMA B-tiles.
// Numerics identical to round-3 (same summation order/epilogue/rounding).
// LDS layouts (halfword index):
//   xb: slot(row,k) = (k>>3)*128 + row*8 + (k&7)           (frag = 8*l)
//   sb: slot(row,k) = (k>>3)*128 + (row^(2*((k>>3)&1)))*8 + (k&7)
//       reader frag = 8*(l ^ 2*(lg&1)); writer slots wbase + 8*(i^psi)
// ---------------------------------------------------------------------------
__global__ __launch_bounds__(256, 1) void augru_fused(
    const float* __restrict__ x,
    const float* __restrict__ state,
    const float* __restrict__ att,
    const float* __restrict__ mask,
    const float* __restrict__ Wau, const float* __restrict__ bau,
    const float* __restrict__ Wbu,
    const float* __restrict__ War, const float* __restrict__ bar,
    const float* __restrict__ Wbr,
    const float* __restrict__ Wac, const float* __restrict__ bac,
    const float* __restrict__ Wbc,
    float* __restrict__ out)
{
  __shared__ bf16_t xb[2][2048];           // x tiles (bf16, frag-linear)
  __shared__ bf16_t sb[2][2048];           // state ping-pong (bf16, swizzled)
  __shared__ float  am_lds[(T_LEN + 1) * 16];  // 1/(att*mask), [t][row], +1 pad

  const int tid = threadIdx.x;
  const int w  = tid >> 6;      // 0..3
  const int l  = tid & 63;
  const int lm = l & 15;
  const int lg = l >> 4;
  const int bb = blockIdx.x;
  const int R0 = bb * 16;
  const int c0 = w * 32 + lm;   // tile 0 column; tile 1 = c0 + 16

  // --- weight B-fragments, [tile][kk] (pre-scaled: u,r by log2e; c by 2log2e)
  BF8 xu[2][4], xr[2][4], xc[2][4];   // x-side  (Wau, War, Wac)
  BF8 su[2][4], sr[2][4], sc[2][4];   // state-side (Wbu, Wbr, Wbc)
  float b_u[2], b_r[2], b_c[2];
#pragma unroll
  for (int tt = 0; tt < 2; ++tt) {
    const int colt = c0 + tt * 16;
#pragma unroll
    for (int kk = 0; kk < 4; ++kk) {
#pragma unroll
      for (int j = 0; j < 8; ++j) {
        int k = kk * 32 + lg * 8 + j;
        xu[tt][kk].e[j] = (bf16_t)(Wau[k * 128 + colt] * LOG2E);
        xr[tt][kk].e[j] = (bf16_t)(War[k * 128 + colt] * LOG2E);
        xc[tt][kk].e[j] = (bf16_t)(Wac[k * 128 + colt] * (2.0f * LOG2E));
        su[tt][kk].e[j] = (bf16_t)(Wbu[k * 128 + colt] * LOG2E);
        sr[tt][kk].e[j] = (bf16_t)(Wbr[k * 128 + colt] * LOG2E);
        sc[tt][kk].e[j] = (bf16_t)(Wbc[k * 128 + colt] * (2.0f * LOG2E));
      }
    }
    b_u[tt] = bau[colt] * LOG2E;
    b_r[tt] = bar[colt] * LOG2E;
    b_c[tt] = bac[colt] * (2.0f * LOG2E);
  }
  const f32x4 biasU[2] = {{b_u[0], b_u[0], b_u[0], b_u[0]},
                          {b_u[1], b_u[1], b_u[1], b_u[1]}};
  const f32x4 biasR[2] = {{b_r[0], b_r[0], b_r[0], b_r[0]},
                          {b_r[1], b_r[1], b_r[1], b_r[1]}};
  const f32x4 biasC[2] = {{b_c[0], b_c[0], b_c[0], b_c[0]},
                          {b_c[1], b_c[1], b_c[1], b_c[1]}};
  const f32x4 zero4 = {0.f, 0.f, 0.f, 0.f};

  // --- 1/(att*mask) preload (row T_LEN is a pad, never used)
  for (int idx = tid; idx < (T_LEN + 1) * 16; idx += 256) {
    int t = idx >> 4; if (t > T_LEN - 1) t = T_LEN - 1;
    int row = idx & 15;
    am_lds[idx] = rcp_f(att[t * B_SZ + R0 + row] * mask[(R0 + row) * T_LEN + t]);
  }

  // --- fp32 state in registers: lane owns (row = lg*4+i, cols c0, c0+16)
  float sreg[2][4];
#pragma unroll
  for (int tt = 0; tt < 2; ++tt)
#pragma unroll
    for (int i = 0; i < 4; ++i)
      sreg[tt][i] = state[(R0 + lg * 4 + i) * 128 + c0 + tt * 16];

  // state bf16 into sb[0], swizzled layout
  for (int idx = tid; idx < 2048; idx += 256) {
    int row = idx >> 7, k = idx & 127;
    sb[0][(k >> 3) * 128 + (row ^ (2 * ((k >> 3) & 1))) * 8 + (k & 7)] =
        (bf16_t)state[(R0 + row) * 128 + k];
  }

  // --- x staging: thread tid stages row=tid&15, float8 chunk sc8=tid>>4
  const int srow = tid & 15;
  const int sc8  = tid >> 4;                       // 0..15
  const int stg_pos = sc8 * 128 + srow * 8;        // halfwords, 16B-aligned
  const float* xrow = x + (size_t)(R0 + srow) * 128 + sc8 * 8;
  const size_t xstep = (size_t)B_SZ * 128;
  const size_t xoff_max = (size_t)(T_LEN - 1) * xstep;

  auto ldf8 = [&](size_t off) {
    F8 q;
    q.a = *(const float4*)(xrow + off);
    q.b = *(const float4*)(xrow + off + 4);
    return q;
  };
  auto stage = [&](int buf, const F8& q) {
    uint4 p;
    p.x = cvt_pk_bf16(q.a.x, q.a.y);
    p.y = cvt_pk_bf16(q.a.z, q.a.w);
    p.z = cvt_pk_bf16(q.b.x, q.b.y);
    p.w = cvt_pk_bf16(q.b.z, q.b.w);
    *(uint4*)&xb[buf][stg_pos] = p;
  };

  // prologue: stage x(0), x(1); register-prefetch x(2), x(3)
  {
    F8 q0 = ldf8(0), q1 = ldf8(xstep);
    stage(0, q0);
    stage(1, q1);
  }
  F8 xqA = ldf8(2 * xstep);   // x(t+2) for even t
  F8 xqB = ldf8(3 * xstep);   // x(t+2) for odd  t
  size_t offA = 4 * xstep;    // next load target for xqA: x(t+4), t even
  size_t offB = 5 * xstep;    // next load target for xqB: x(t+4), t odd

  __syncthreads();   // full drain once

  // x-gates(0) from xb[0] into registers (both tiles)
  f32x4 gU[2], gR[2], gC[2];
  {
    bf16x8 ax[4];
#pragma unroll
    for (int kk = 0; kk < 4; ++kk)
      ax[kk] = *(const bf16x8*)&xb[0][kk * 512 + 8 * l];
#pragma unroll
    for (int tt = 0; tt < 2; ++tt) {
      gU[tt] = __builtin_amdgcn_mfma_f32_16x16x32_bf16(ax[0], xu[tt][0].v, biasU[tt], 0, 0, 0);
      gR[tt] = __builtin_amdgcn_mfma_f32_16x16x32_bf16(ax[0], xr[tt][0].v, biasR[tt], 0, 0, 0);
      gC[tt] = __builtin_amdgcn_mfma_f32_16x16x32_bf16(ax[0], xc[tt][0].v, biasC[tt], 0, 0, 0);
    }
#pragma unroll
    for (int kk = 1; kk < 4; ++kk)
#pragma unroll
      for (int tt = 0; tt < 2; ++tt) {
        gU[tt] = __builtin_amdgcn_mfma_f32_16x16x32_bf16(ax[kk], xu[tt][kk].v, gU[tt], 0, 0, 0);
        gR[tt] = __builtin_amdgcn_mfma_f32_16x16x32_bf16(ax[kk], xr[tt][kk].v, gR[tt], 0, 0, 0);
        gC[tt] = __builtin_amdgcn_mfma_f32_16x16x32_bf16(ax[kk], xc[tt][kk].v, gC[tt], 0, 0, 0);
      }
  }
  union F4 { float4 v; float e[4]; } amv, amn;
  amv.v = *(const float4*)&am_lds[lg * 4];           // ia(0)
  const float* am_ptr = &am_lds[16 + lg * 4];        // walking ptr: ia(t+1)

  const int lx8   = 8 * (l ^ (2 * (lg & 1)));        // swizzled sb frag offset
  const int psi   = 2 * ((c0 >> 3) & 1);             // writer value permutation
  const int wbase = (c0 >> 3) * 128 + lg * 32 + (c0 & 7);  // tile1: +256

  BAR_LDS();   // protect xb[0] before step 0 overwrites it

  // One scan step. xq = x(t+2) register buffer (statically renamed by the
  // caller's 2-step unroll); after staging it, reload it with x(t+4).
  auto step = [&](int t, F8& xq, size_t& xoff) {
    const int rp = t & 1;

    // fragment ds_reads issue FIRST: state frags s(t), then x frags x(t+1)
    bf16x8 as_[4], ax[4];
#pragma unroll
    for (int kk = 0; kk < 4; ++kk)
      as_[kk] = *(const bf16x8*)&sb[rp][kk * 512 + lx8];
#pragma unroll
    for (int kk = 0; kk < 4; ++kk)
      ax[kk]  = *(const bf16x8*)&xb[rp ^ 1][kk * 512 + 8 * l];

    // ia(t+1) prefetch early (drains long before the barrier)
    amn.v = *(const float4*)am_ptr;
    am_ptr += 16;

    // stage x(t+2) into xb[rp]; then reload this buffer with x(t+4)
    stage(rp, xq);
    xq = ldf8(xoff);
    xoff += 2 * xstep; if (xoff > xoff_max) xoff = xoff_max;

    // state-side MFMAs first (critical path); 6 independent chains (3 gates
    // x 2 tiles). First MFMA of each chain takes the persistent/gate reg as C.
    f32x4 aU[2], aR[2], bC[2];
#pragma unroll
    for (int tt = 0; tt < 2; ++tt) {
      aU[tt] = __builtin_amdgcn_mfma_f32_16x16x32_bf16(as_[0], su[tt][0].v, gU[tt], 0, 0, 0);
      aR[tt] = __builtin_amdgcn_mfma_f32_16x16x32_bf16(as_[0], sr[tt][0].v, gR[tt], 0, 0, 0);
      bC[tt] = __builtin_amdgcn_mfma_f32_16x16x32_bf16(as_[0], sc[tt][0].v, zero4, 0, 0, 0);
    }
#pragma unroll
    for (int kk = 1; kk < 4; ++kk)
#pragma unroll
      for (int tt = 0; tt < 2; ++tt) {
        aU[tt] = __builtin_amdgcn_mfma_f32_16x16x32_bf16(as_[kk], su[tt][kk].v, aU[tt], 0, 0, 0);
        aR[tt] = __builtin_amdgcn_mfma_f32_16x16x32_bf16(as_[kk], sr[tt][kk].v, aR[tt], 0, 0, 0);
        bC[tt] = __builtin_amdgcn_mfma_f32_16x16x32_bf16(as_[kk], sc[tt][kk].v, bC[tt], 0, 0, 0);
      }
    // x-side gates for t+1 (off critical path)
    f32x4 nU[2], nR[2], nC[2];
#pragma unroll
    for (int tt = 0; tt < 2; ++tt) {
      nU[tt] = __builtin_amdgcn_mfma_f32_16x16x32_bf16(ax[0], xu[tt][0].v, biasU[tt], 0, 0, 0);
      nR[tt] = __builtin_amdgcn_mfma_f32_16x16x32_bf16(ax[0], xr[tt][0].v, biasR[tt], 0, 0, 0);
      nC[tt] = __builtin_amdgcn_mfma_f32_16x16x32_bf16(ax[0], xc[tt][0].v, biasC[tt], 0, 0, 0);
    }
#pragma unroll
    for (int kk = 1; kk < 4; ++kk)
#pragma unroll
      for (int tt = 0; tt < 2; ++tt) {
        nU[tt] = __builtin_amdgcn_mfma_f32_16x16x32_bf16(ax[kk], xu[tt][kk].v, nU[tt], 0, 0, 0);
        nR[tt] = __builtin_amdgcn_mfma_f32_16x16x32_bf16(ax[kk], xr[tt][kk].v, nR[tt], 0, 0, 0);
        nC[tt] = __builtin_amdgcn_mfma_f32_16x16x32_bf16(ax[kk], xc[tt][kk].v, nC[tt], 0, 0, 0);
      }

    bf16_t* wbuf = sb[rp ^ 1];
#pragma unroll
    for (int tt = 0; tt < 2; ++tt) {
      const int wb = wbase + tt * 256;
#pragma unroll
      for (int i = 0; i < 4; ++i) {
        // k = am * sigmoid(aU) = rcp((1 + 2^-aU) * ia), ia = 1/am
        float Xu = __builtin_amdgcn_exp2f(-aU[tt][i]);
        float k  = rcp_f(fmaf(Xu, amv.e[i], amv.e[i]));
        float r  = rcp_f(1.0f + __builtin_amdgcn_exp2f(-aR[tt][i]));
        float wc = fmaf(r, bC[tt][i], gC[tt][i]);
        float cg = fmaf(-2.0f, rcp_f(__builtin_amdgcn_exp2f(wc) + 1.0f), 1.0f);
        float sf = fmaf(k, cg - sreg[tt][i], sreg[tt][i]);
        sreg[tt][i] = sf;
        wbuf[wb + 8 * (i ^ psi)] = (bf16_t)sf;
      }
    }

    // rotate pipelined registers
#pragma unroll
    for (int tt = 0; tt < 2; ++tt) {
      gU[tt] = nU[tt]; gR[tt] = nR[tt]; gC[tt] = nC[tt];
    }
    amv.v = amn.v;

    BAR_LDS();
  };

#pragma unroll 1
  for (int t = 0; t < T_LEN; t += 2) {
    step(t,     xqA, offA);
    step(t + 1, xqB, offB);
  }

#pragma unroll
  for (int tt = 0; tt < 2; ++tt)
#pragma unroll
    for (int i = 0; i < 4; ++i)
      out[(R0 + lg * 4 + i) * 128 + c0 + tt * 16] = sreg[tt][i];
}

// ---------------------------------------------------------------------------
extern "C" void kernel_launch(void* const* d_in, const int* in_sizes, int n_in,
                              void* d_out, int out_size, void* d_ws, size_t ws_size,
                              hipStream_t stream)
{
  const float* x    = (const float*)d_in[0];
  const float* st   = (const float*)d_in[1];
  const float* att  = (const float*)d_in[2];
  const float* mask = (const float*)d_in[3];
  // d_in[4] = max_len (unused; shapes hard-coded)
  const float* Wau  = (const float*)d_in[5];
  const float* bau  = (const float*)d_in[6];
  const float* Wbu  = (const float*)d_in[7];
  const float* War  = (const float*)d_in[8];
  const float* bar  = (const float*)d_in[9];
  const float* Wbr  = (const float*)d_in[10];
  const float* Wac  = (const float*)d_in[11];
  const float* bac  = (const float*)d_in[12];
  const float* Wbc  = (const float*)d_in[13];

  (void)d_ws; (void)ws_size;

  augru_fused<<<dim3(64), dim3(256), 0, stream>>>(
      x, st, att, mask, Wau, bau, Wbu, War, bar, Wbr, Wac, bac, Wbc,
      (float*)d_out);
}

// Round 5
// 294.089 us; speedup vs baseline: 1.1501x; 1.1501x over previous
//
#include <hip/hip_runtime.h>
#include <stdint.h>

#define T_LEN 200
#define B_SZ  1024
#define D_DIM 128
#define LOG2E 1.44269504088896340736f

typedef __bf16 bf16_t;
typedef __bf16 bf16x8 __attribute__((ext_vector_type(8)));
typedef float  f32x4  __attribute__((ext_vector_type(4)));

union BF8 { bf16x8 v; bf16_t e[8]; };

__device__ inline float rcp_f(float x) { return __builtin_amdgcn_rcpf(x); }

// Pack two f32 -> bf16x2 dword, RNE (single HW instr).
__device__ inline uint32_t cvt_pk_bf16(float a, float b) {
  uint32_t r;
  asm("v_cvt_pk_bf16_f32 %0, %1, %2" : "=v"(r) : "v"(a), "v"(b));
  return r;
}

// LDS-only barrier: wait LDS ops, leave global loads (vmcnt) in flight.
#define BAR_LDS() asm volatile("s_waitcnt lgkmcnt(0)\n\ts_barrier" ::: "memory")

// ---------------------------------------------------------------------------
// Fused AUGRU scan. Round-5: revert to the 8-wave x 16-col structure (R3,
// 161us) -- R4 proved 2 waves/SIMD of latency-hiding outweigh LDS traffic --
// and restructure the step around the SERIAL CHAIN:
//   barrier -> ds_read(s) -> state MFMAs -> epilogue -> ds_write(s) -> barrier
// Everything off that chain (x-frag reads, 12 x-side MFMAs, x staging, am/xq
// prefetches) now sits AFTER the epilogue in program order, so the wave
// reaches the epilogue ~60-100cy earlier and the post-write tail covers the
// ds_write latency before the barrier. State MFMAs interleave aR,bC first
// (epilogue's longest chain starts from aR). All chains keep their internal
// summation order -> bit-identical numerics to R3.
// 64 blocks x 512 threads; block bb owns batch rows [16*bb, 16*bb+16).
// LDS layouts (halfword index):
//   xb: slot(row,k) = (k>>3)*128 + row*8 + (k&7)           (frag = 8*l)
//   sb: slot(row,k) = (k>>3)*128 + (row^(2*((k>>3)&1)))*8 + (k&7)
//       reader frag = 8*(l ^ 2*(lg&1)); writer slots wbase + 8*(i^psi)
// ---------------------------------------------------------------------------
__global__ __launch_bounds__(512, 2) void augru_fused(
    const float* __restrict__ x,
    const float* __restrict__ state,
    const float* __restrict__ att,
    const float* __restrict__ mask,
    const float* __restrict__ Wau, const float* __restrict__ bau,
    const float* __restrict__ Wbu,
    const float* __restrict__ War, const float* __restrict__ bar,
    const float* __restrict__ Wbr,
    const float* __restrict__ Wac, const float* __restrict__ bac,
    const float* __restrict__ Wbc,
    float* __restrict__ out)
{
  __shared__ bf16_t xb[2][2048];           // x tiles (bf16, frag-linear)
  __shared__ bf16_t sb[2][2048];           // state ping-pong (bf16, swizzled)
  __shared__ float  am_lds[(T_LEN + 1) * 16];  // 1/(att*mask), [t][row], +1 pad

  const int tid = threadIdx.x;
  const int w  = tid >> 6;
  const int l  = tid & 63;
  const int lm = l & 15;
  const int lg = l >> 4;
  const int bb = blockIdx.x;
  const int R0 = bb * 16;
  const int col = w * 16 + lm;

  // --- weight B-fragments in registers (pre-scaled: u,r by log2e; c by 2log2e)
  BF8 xu[4], xr[4], xc[4];   // x-side  (Wau, War, Wac)
  BF8 su[4], sr[4], sc[4];   // state-side (Wbu, Wbr, Wbc)
#pragma unroll
  for (int kk = 0; kk < 4; ++kk) {
#pragma unroll
    for (int j = 0; j < 8; ++j) {
      int k = kk * 32 + lg * 8 + j;
      xu[kk].e[j] = (bf16_t)(Wau[k * 128 + col] * LOG2E);
      xr[kk].e[j] = (bf16_t)(War[k * 128 + col] * LOG2E);
      xc[kk].e[j] = (bf16_t)(Wac[k * 128 + col] * (2.0f * LOG2E));
      su[kk].e[j] = (bf16_t)(Wbu[k * 128 + col] * LOG2E);
      sr[kk].e[j] = (bf16_t)(Wbr[k * 128 + col] * LOG2E);
      sc[kk].e[j] = (bf16_t)(Wbc[k * 128 + col] * (2.0f * LOG2E));
    }
  }
  const float b_u = bau[col] * LOG2E;
  const float b_r = bar[col] * LOG2E;
  const float b_c = bac[col] * (2.0f * LOG2E);

  // persistent C-operand sources (never overwritten by MFMA)
  const f32x4 biasU = {b_u, b_u, b_u, b_u};
  const f32x4 biasR = {b_r, b_r, b_r, b_r};
  const f32x4 biasC = {b_c, b_c, b_c, b_c};
  const f32x4 zero4 = {0.f, 0.f, 0.f, 0.f};

  // --- 1/(att*mask) preload (row T_LEN is a pad, never used)
  for (int idx = tid; idx < (T_LEN + 1) * 16; idx += 512) {
    int t = idx >> 4; if (t > T_LEN - 1) t = T_LEN - 1;
    int row = idx & 15;
    am_lds[idx] = rcp_f(att[t * B_SZ + R0 + row] * mask[(R0 + row) * T_LEN + t]);
  }

  // --- fp32 state in registers: lane owns (row = lg*4+i, col)
  float sreg[4];
#pragma unroll
  for (int i = 0; i < 4; ++i)
    sreg[i] = state[(R0 + lg * 4 + i) * 128 + col];

  // state bf16 into sb[0], swizzled layout
  for (int idx = tid; idx < 2048; idx += 512) {
    int row = idx >> 7, k = idx & 127;
    sb[0][(k >> 3) * 128 + (row ^ (2 * ((k >> 3) & 1))) * 8 + (k & 7)] =
        (bf16_t)state[(R0 + row) * 128 + k];
  }

  // --- x staging: thread tid stages row=tid&15, float4 chunk sc4=tid>>4
  const int srow = tid & 15;
  const int sc4  = tid >> 4;
  const int stg_pos = (sc4 >> 1) * 128 + srow * 8 + (sc4 & 1) * 4;  // halfwords
  const float* xrow = x + (size_t)(R0 + srow) * 128 + sc4 * 4;
  const size_t xstep = (size_t)B_SZ * 128;
  const size_t xoff_max = (size_t)(T_LEN - 1) * xstep;

  // prologue: stage x(0), x(1); register-prefetch x(2), x(3)
  {
    float4 v0 = *(const float4*)(xrow);
    float4 v1 = *(const float4*)(xrow + xstep);
    uint2 p0, p1;
    p0.x = cvt_pk_bf16(v0.x, v0.y); p0.y = cvt_pk_bf16(v0.z, v0.w);
    p1.x = cvt_pk_bf16(v1.x, v1.y); p1.y = cvt_pk_bf16(v1.z, v1.w);
    *(uint2*)&xb[0][stg_pos] = p0;
    *(uint2*)&xb[1][stg_pos] = p1;
  }
  float4 xqA = *(const float4*)(xrow + 2 * xstep);   // x(t+2) for even t
  float4 xqB = *(const float4*)(xrow + 3 * xstep);   // x(t+2) for odd  t
  size_t offA = 4 * xstep;   // next load target for xqA: x(t+4), t even
  size_t offB = 5 * xstep;   // next load target for xqB: x(t+4), t odd

  __syncthreads();   // full drain once

  // x-gates(0) from xb[0] into registers
  f32x4 gU, gR, gC;
  {
    bf16x8 ax[4];
#pragma unroll
    for (int kk = 0; kk < 4; ++kk)
      ax[kk] = *(const bf16x8*)&xb[0][kk * 512 + 8 * l];
    gU = __builtin_amdgcn_mfma_f32_16x16x32_bf16(ax[0], xu[0].v, biasU, 0, 0, 0);
    gR = __builtin_amdgcn_mfma_f32_16x16x32_bf16(ax[0], xr[0].v, biasR, 0, 0, 0);
    gC = __builtin_amdgcn_mfma_f32_16x16x32_bf16(ax[0], xc[0].v, biasC, 0, 0, 0);
#pragma unroll
    for (int kk = 1; kk < 4; ++kk) {
      gU = __builtin_amdgcn_mfma_f32_16x16x32_bf16(ax[kk], xu[kk].v, gU, 0, 0, 0);
      gR = __builtin_amdgcn_mfma_f32_16x16x32_bf16(ax[kk], xr[kk].v, gR, 0, 0, 0);
      gC = __builtin_amdgcn_mfma_f32_16x16x32_bf16(ax[kk], xc[kk].v, gC, 0, 0, 0);
    }
  }
  union F4 { float4 v; float e[4]; } amv, amn;
  amv.v = *(const float4*)&am_lds[lg * 4];           // ia(0)
  const float* am_ptr = &am_lds[16 + lg * 4];        // walking ptr: ia(t+1)

  const int lx8   = 8 * (l ^ (2 * (lg & 1)));        // swizzled sb frag offset
  const int psi   = 2 * ((col >> 3) & 1);            // writer value permutation
  const int wbase = (col >> 3) * 128 + lg * 32 + (col & 7);

  BAR_LDS();   // protect xb[0] before step 0 overwrites it

  // One scan step. xq = x(t+2) register buffer (statically renamed by the
  // caller's 2-step unroll); after staging it, reload it with x(t+4).
  auto step = [&](int t, float4& xq, size_t& xoff) {
    const int rp = t & 1;

    // ---- CRITICAL CHAIN: s-frag reads -> state MFMAs -> epilogue -> write
    bf16x8 as_[4];
#pragma unroll
    for (int kk = 0; kk < 4; ++kk)
      as_[kk] = *(const bf16x8*)&sb[rp][kk * 512 + lx8];

    // state-side MFMAs; aR/bC issued first (epilogue's longest chain starts
    // from aR). First MFMA of each chain takes the persistent/gate reg as C.
    // Summation order within each chain identical to R3 (bit-identical).
    f32x4 aR = __builtin_amdgcn_mfma_f32_16x16x32_bf16(as_[0], sr[0].v, gR, 0, 0, 0);
    f32x4 bC = __builtin_amdgcn_mfma_f32_16x16x32_bf16(as_[0], sc[0].v, zero4, 0, 0, 0);
    f32x4 aU = __builtin_amdgcn_mfma_f32_16x16x32_bf16(as_[0], su[0].v, gU, 0, 0, 0);
#pragma unroll
    for (int kk = 1; kk < 4; ++kk) {
      aR = __builtin_amdgcn_mfma_f32_16x16x32_bf16(as_[kk], sr[kk].v, aR, 0, 0, 0);
      bC = __builtin_amdgcn_mfma_f32_16x16x32_bf16(as_[kk], sc[kk].v, bC, 0, 0, 0);
      aU = __builtin_amdgcn_mfma_f32_16x16x32_bf16(as_[kk], su[kk].v, aU, 0, 0, 0);
    }

    bf16_t* wbuf = sb[rp ^ 1];
#pragma unroll
    for (int i = 0; i < 4; ++i) {
      // k = am * sigmoid(aU) = rcp((1 + 2^-aU) * ia), ia = 1/am
      float Xr = __builtin_amdgcn_exp2f(-aR[i]);      // longest chain first
      float Xu = __builtin_amdgcn_exp2f(-aU[i]);
      float r  = rcp_f(1.0f + Xr);
      float k  = rcp_f(fmaf(Xu, amv.e[i], amv.e[i]));
      float wc = fmaf(r, bC[i], gC[i]);
      float cg = fmaf(-2.0f, rcp_f(__builtin_amdgcn_exp2f(wc) + 1.0f), 1.0f);
      float sf = fmaf(k, cg - sreg[i], sreg[i]);
      sreg[i] = sf;
      wbuf[wbase + 8 * (i ^ psi)] = (bf16_t)sf;
    }

    // ---- OFF-CHAIN TAIL (covers ds_write latency before the barrier) ----
    // x-frag reads for t+1 (from the buffer staged at t-1; not written here)
    bf16x8 ax[4];
#pragma unroll
    for (int kk = 0; kk < 4; ++kk)
      ax[kk] = *(const bf16x8*)&xb[rp ^ 1][kk * 512 + 8 * l];

    // x-side gates for t+1
    f32x4 nU = __builtin_amdgcn_mfma_f32_16x16x32_bf16(ax[0], xu[0].v, biasU, 0, 0, 0);
    f32x4 nR = __builtin_amdgcn_mfma_f32_16x16x32_bf16(ax[0], xr[0].v, biasR, 0, 0, 0);
    f32x4 nC = __builtin_amdgcn_mfma_f32_16x16x32_bf16(ax[0], xc[0].v, biasC, 0, 0, 0);
#pragma unroll
    for (int kk = 1; kk < 4; ++kk) {
      nU = __builtin_amdgcn_mfma_f32_16x16x32_bf16(ax[kk], xu[kk].v, nU, 0, 0, 0);
      nR = __builtin_amdgcn_mfma_f32_16x16x32_bf16(ax[kk], xr[kk].v, nR, 0, 0, 0);
      nC = __builtin_amdgcn_mfma_f32_16x16x32_bf16(ax[kk], xc[kk].v, nC, 0, 0, 0);
    }

    // stage x(t+2) into xb[rp]; reload this buffer with x(t+4)
    {
      uint2 p;
      p.x = cvt_pk_bf16(xq.x, xq.y);
      p.y = cvt_pk_bf16(xq.z, xq.w);
      *(uint2*)&xb[rp][stg_pos] = p;
    }
    xq = *(const float4*)(xrow + xoff);
    xoff += 2 * xstep; if (xoff > xoff_max) xoff = xoff_max;

    // ia(t+1) prefetch
    amn.v = *(const float4*)am_ptr;
    am_ptr += 16;

    // rotate pipelined registers
    gU = nU; gR = nR; gC = nC;
    amv.v = amn.v;

    BAR_LDS();
  };

#pragma unroll 1
  for (int t = 0; t < T_LEN; t += 2) {
    step(t,     xqA, offA);
    step(t + 1, xqB, offB);
  }

#pragma unroll
  for (int i = 0; i < 4; ++i)
    out[(R0 + lg * 4 + i) * 128 + col] = sreg[i];
}

// ---------------------------------------------------------------------------
extern "C" void kernel_launch(void* const* d_in, const int* in_sizes, int n_in,
                              void* d_out, int out_size, void* d_ws, size_t ws_size,
                              hipStream_t stream)
{
  const float* x    = (const float*)d_in[0];
  const float* st   = (const float*)d_in[1];
  const float* att  = (const float*)d_in[2];
  const float* mask = (const float*)d_in[3];
  // d_in[4] = max_len (unused; shapes hard-coded)
  const float* Wau  = (const float*)d_in[5];
  const float* bau  = (const float*)d_in[6];
  const float* Wbu  = (const float*)d_in[7];
  const float* War  = (const float*)d_in[8];
  const float* bar  = (const float*)d_in[9];
  const float* Wbr  = (const float*)d_in[10];
  const float* Wac  = (const float*)d_in[11];
  const float* bac  = (const float*)d_in[12];
  const float* Wbc  = (const float*)d_in[13];

  (void)d_ws; (void)ws_size;

  augru_fused<<<dim3(64), dim3(512), 0, stream>>>(
      x, st, att, mask, Wau, bau, Wbu, War, bar, Wbr, Wac, bac, Wbc,
      (float*)d_out);
}